// Round 4
// baseline (506.457 us; speedup 1.0000x reference)
//
#include <hip/hip_runtime.h>
#include <cmath>

// ---------------- problem constants ----------------
#define NLAYERS 100      // hidden layers (scan)
#define DIN     64       // input features
#define WDIM    100      // hidden width
#define NPAD    112      // padded N (7 tiles of 16)
#define NT      7        // n tiles
#define ROWS    16       // rows per wave -> 4096 waves
#define PSTR    120      // f16 plane row stride (240 B: keeps ds_read_b128 16-aligned)
#define PLANE   (16 * PSTR)   // one plane = 1920 f16 = 3840 B; hi+lo = 7680 B

typedef _Float16 half8 __attribute__((ext_vector_type(8)));
typedef __fp16   fp16x2 __attribute__((ext_vector_type(2)));   // cvt_pkrtz return type
typedef float    f32x4 __attribute__((ext_vector_type(4)));

// ---------------- workspace layout ----------------
#define WSH_LAYER_HALVES (NT * 4 * 64 * 8)               // 14336 halves per hidden layer
#define WSH_HALVES       (NLAYERS * WSH_LAYER_HALVES)    // 1,433,600
#define W0_HALVES        (NT * 2 * 64 * 8)               // 7168 (input layer, K=64)
#define BPAD_FLOATS      ((NLAYERS + 1) * NPAD)          // 11312
#define OFF_BPAD_B       ((WSH_HALVES + W0_HALVES) * 2)  // bytes, 16-aligned
#define OFF_WOUT_B       (OFF_BPAD_B + BPAD_FLOATS * 4)  // bytes, 16-aligned
#define TOTAL_PREP       (WSH_HALVES + W0_HALVES + BPAD_FLOATS + NPAD)

// ============================================================
// Prep: shuffle weights into exact MFMA B-fragment order (f16),
// pad biases / W_out. Re-run every launch (ws is re-poisoned).
// B-frag for (nt,ks): lane(q=lane>>4,l15=lane&15), elem j ->
//   B[k = ks*32 + q*8 + j][n = nt*16 + l15]
// ============================================================
__global__ void actor_prep(const float* __restrict__ Win, const float* __restrict__ bin,
                           const float* __restrict__ Ws,  const float* __restrict__ bs,
                           const float* __restrict__ Wout,
                           _Float16* __restrict__ wsh, _Float16* __restrict__ w0sh,
                           float* __restrict__ bpad, float* __restrict__ woutp) {
    int t = blockIdx.x * 256 + threadIdx.x;
    if (t < WSH_HALVES) {                       // hidden-layer weights
        int j    = t & 7;
        int lane = (t >> 3) & 63;
        int ks   = (t >> 9) & 3;
        int rest = t >> 11;                     // l*7 + nt
        int nt   = rest % 7;
        int l    = rest / 7;
        int qq = lane >> 4, ll = lane & 15;
        int k = ks * 32 + qq * 8 + j;
        int n = nt * 16 + ll;
        float v = (k < WDIM && n < WDIM) ? Ws[(l * WDIM + k) * WDIM + n] : 0.f;
        wsh[t] = (_Float16)v;
        return;
    }
    int t2 = t - WSH_HALVES;
    if (t2 < W0_HALVES) {                       // input layer weights (K=64)
        int j    = t2 & 7;
        int lane = (t2 >> 3) & 63;
        int ks   = (t2 >> 9) & 1;
        int nt   = t2 >> 10;
        int qq = lane >> 4, ll = lane & 15;
        int k = ks * 32 + qq * 8 + j;
        int n = nt * 16 + ll;
        float v = (k < DIN && n < WDIM) ? Win[k * WDIM + n] : 0.f;
        w0sh[t2] = (_Float16)v;
        return;
    }
    int t3 = t2 - W0_HALVES;
    if (t3 < BPAD_FLOATS) {                     // padded biases: row 0 = b_in, rows 1..100 = bs
        int l = t3 / NPAD, c = t3 % NPAD;
        float v = 0.f;
        if (c < WDIM) v = (l == 0) ? bin[c] : bs[(l - 1) * WDIM + c];
        bpad[t3] = v;
        return;
    }
    int t4 = t3 - BPAD_FLOATS;
    if (t4 < NPAD) woutp[t4] = (t4 < WDIM) ? Wout[t4] : 0.f;
}

// split fp32 -> hi/lo fp16 (layer-0 only; hidden layers split at epilogue).
__device__ __forceinline__ void split8(const float* __restrict__ p, half8& hi, half8& lo) {
    f32x4 u0 = *(const f32x4*)p;
    f32x4 u1 = *(const f32x4*)(p + 4);
    float v[8] = {u0[0], u0[1], u0[2], u0[3], u1[0], u1[1], u1[2], u1[3]};
#pragma unroll
    for (int e = 0; e < 8; e += 2) {
        fp16x2 h = __builtin_amdgcn_cvt_pkrtz(v[e], v[e + 1]);
        float r0 = v[e]     - (float)h[0];
        float r1 = v[e + 1] - (float)h[1];
        fp16x2 l = __builtin_amdgcn_cvt_pkrtz(r0, r1);
        hi[e] = (_Float16)h[0]; hi[e + 1] = (_Float16)h[1];
        lo[e] = (_Float16)l[0]; lo[e + 1] = (_Float16)l[1];
    }
}

// ============================================================
// Main: one wave per block, 16 rows, whole network fused.
// h kept as TWO f16 PLANES (hi, lo) in LDS: A-frag read = bare
// ds_read_b128, ZERO VALU on the read side (the round-3 VALU hog).
// Split fp32->hi/lo happens once per value in the epilogue.
// Weights read as pre-shuffled global B-frags (L1-hot, pipelined 1
// k-step ahead). Per (ks,nt): hi-MFMA; lo-MFMA skipped at ks=3
// (corrects only k=96..99: numerically negligible) -> 49 MFMAs/layer.
// No barriers (1 wave owns its h planes).
// ============================================================
__global__ __launch_bounds__(64, 4)
void actor_main(const float* __restrict__ x,
                const _Float16* __restrict__ wsh,
                const _Float16* __restrict__ w0sh,
                const float* __restrict__ bpad,
                const float* __restrict__ woutp,
                const float* __restrict__ bout,
                float* __restrict__ out) {
    __shared__ _Float16 hp[2 * PLANE];   // [0,PLANE): hi plane; [PLANE,2*PLANE): lo plane
    const int lane = threadIdx.x;
    const int q = lane >> 4, l15 = lane & 15;
    const int rowbase = blockIdx.x * ROWS;

    f32x4 acc[NT];
    half8 bb[2][NT];                 // double-buffered B fragments (prefetch 1 k-step ahead)
    const f32x4 zero4 = {0.f, 0.f, 0.f, 0.f};
    const half8 zeroh = {0, 0, 0, 0, 0, 0, 0, 0};

#pragma unroll
    for (int nt = 0; nt < NT; ++nt) acc[nt] = zero4;

    // preload input-layer ks=0 B frags
#pragma unroll
    for (int nt = 0; nt < NT; ++nt)
        bb[0][nt] = *(const half8*)(w0sh + ((nt * 2 + 0) * 64 + lane) * 8);

    // ---------------- layer 0: x @ W_in (K=64), split from global x ----------------
#pragma unroll
    for (int ks = 0; ks < 2; ++ks) {
        const int cur = ks & 1, nxt = cur ^ 1;
        if (ks == 0) {               // prefetch ks=1
#pragma unroll
            for (int nt = 0; nt < NT; ++nt)
                bb[nxt][nt] = *(const half8*)(w0sh + ((nt * 2 + 1) * 64 + lane) * 8);
        } else {                     // prefetch hidden layer 0, ks=0
#pragma unroll
            for (int nt = 0; nt < NT; ++nt)
                bb[nxt][nt] = *(const half8*)(wsh + ((nt * 4 + 0) * 64 + lane) * 8);
        }
        half8 ahi, alo;
        split8(x + (rowbase + l15) * DIN + ks * 32 + q * 8, ahi, alo);
#pragma unroll
        for (int nt = 0; nt < NT; ++nt) {
            acc[nt] = __builtin_amdgcn_mfma_f32_16x16x32_f16(ahi, bb[cur][nt], acc[nt], 0, 0, 0);
            acc[nt] = __builtin_amdgcn_mfma_f32_16x16x32_f16(alo, bb[cur][nt], acc[nt], 0, 0, 0);
        }
    }
    // epilogue 0: bias + leaky + split -> hi/lo planes (cols 100..111 exact zeros)
#pragma unroll
    for (int nt = 0; nt < NT; ++nt) {
        const int col = nt * 16 + l15;
        const float bbias = bpad[col];
#pragma unroll
        for (int r = 0; r < 4; ++r) {
            float t = acc[nt][r] + bbias;
            float v = fmaxf(t, 0.01f * t);
            _Float16 h = (_Float16)v;            // RNE hi
            _Float16 lo = (_Float16)(v - (float)h);
            const int idx = (q * 4 + r) * PSTR + col;
            hp[idx] = h;
            hp[PLANE + idx] = lo;
        }
    }

    // ---------------- 100 hidden layers ----------------
#pragma unroll 1
    for (int l = 0; l < NLAYERS; ++l) {
        const _Float16* wl = wsh + l * WSH_LAYER_HALVES;
        const _Float16* wlnext = wsh + (l < NLAYERS - 1 ? l + 1 : l) * WSH_LAYER_HALVES;
#pragma unroll
        for (int nt = 0; nt < NT; ++nt) acc[nt] = zero4;

#pragma unroll
        for (int ks = 0; ks < 4; ++ks) {
            const int cur = ks & 1, nxt = cur ^ 1;
            // prefetch next k-step (or next layer's ks=0) B frags
            const _Float16* src = (ks < 3) ? (wl + ((ks + 1) * 64 + lane) * 8)
                                           : (wlnext + (lane) * 8);
#pragma unroll
            for (int nt = 0; nt < NT; ++nt)
                bb[nxt][nt] = *(const half8*)(src + nt * 4 * 64 * 8);

            // hi fragment: bare b128 read from hi plane (zero VALU)
            half8 ahi;
            if (ks == 3 && q >= 2) {             // k in [112,128): pad region, must mask
                ahi = zeroh;
            } else {
                ahi = *(const half8*)(hp + l15 * PSTR + ks * 32 + q * 8);
            }
#pragma unroll
            for (int nt = 0; nt < NT; ++nt)
                acc[nt] = __builtin_amdgcn_mfma_f32_16x16x32_f16(ahi, bb[cur][nt], acc[nt], 0, 0, 0);

            if (ks < 3) {                        // lo correction (skip ks=3: only k 96..99, negligible)
                half8 alo = *(const half8*)(hp + PLANE + l15 * PSTR + ks * 32 + q * 8);
#pragma unroll
                for (int nt = 0; nt < NT; ++nt)
                    acc[nt] = __builtin_amdgcn_mfma_f32_16x16x32_f16(alo, bb[cur][nt], acc[nt], 0, 0, 0);
            }
        }
        // epilogue: bias + leaky + split -> hi/lo planes
        const float* brow = bpad + (l + 1) * NPAD;
#pragma unroll
        for (int nt = 0; nt < NT; ++nt) {
            const int col = nt * 16 + l15;
            const float bbias = brow[col];
#pragma unroll
            for (int r = 0; r < 4; ++r) {
                float t = acc[nt][r] + bbias;
                float v = fmaxf(t, 0.01f * t);
                _Float16 h = (_Float16)v;
                _Float16 lo = (_Float16)(v - (float)h);
                const int idx = (q * 4 + r) * PSTR + col;
                hp[idx] = h;
                hp[PLANE + idx] = lo;
            }
        }
    }

    // ---------------- head: dot(h, W_out) + b_out, tanh, affine ----------------
    {
        const int row = lane >> 2, hf = lane & 3;   // 4 lanes per row, 28 cols each
        float s = 0.f;
#pragma unroll
        for (int i = 0; i < 28; ++i) {
            const int c = hf * 28 + i;
            float v = (float)hp[row * PSTR + c] + (float)hp[PLANE + row * PSTR + c];
            s += v * woutp[c];
        }
        s += __shfl_xor(s, 1);
        s += __shfl_xor(s, 2);
        if (hf == 0) {
            float a = s + bout[0];
            float t = tanhf(a);
            out[rowbase + row] = t * 4.5f + 5.5f;   // (tanh+1)/2*9 + 1
        }
    }
}

extern "C" void kernel_launch(void* const* d_in, const int* in_sizes, int n_in,
                              void* d_out, int out_size, void* d_ws, size_t ws_size,
                              hipStream_t stream) {
    const float* x    = (const float*)d_in[0];
    const float* Win  = (const float*)d_in[1];
    const float* bin  = (const float*)d_in[2];
    const float* Ws   = (const float*)d_in[3];
    const float* bs   = (const float*)d_in[4];
    const float* Wout = (const float*)d_in[5];
    const float* bout = (const float*)d_in[6];
    float* out = (float*)d_out;

    char* ws = (char*)d_ws;
    _Float16* wsh  = (_Float16*)ws;
    _Float16* w0sh = wsh + WSH_HALVES;
    float* bpad  = (float*)(ws + OFF_BPAD_B);
    float* woutp = (float*)(ws + OFF_WOUT_B);

    hipLaunchKernelGGL(actor_prep, dim3((TOTAL_PREP + 255) / 256), dim3(256), 0, stream,
                       Win, bin, Ws, bs, Wout, wsh, w0sh, bpad, woutp);

    const int nrows = in_sizes[0] / DIN;   // 65536
    hipLaunchKernelGGL(actor_main, dim3(nrows / ROWS), dim3(64), 0, stream,
                       x, wsh, w0sh, bpad, woutp, bout, out);
}

// Round 5
// 471.687 us; speedup vs baseline: 1.0737x; 1.0737x over previous
//
#include <hip/hip_runtime.h>
#include <cmath>

// ---------------- problem constants ----------------
#define NLAYERS 100      // hidden layers (scan)
#define DIN     64       // input features
#define WDIM    100      // hidden width
#define NPAD    112      // padded N (7 tiles of 16)
#define NT      7        // n tiles
#define ROWS    16       // batch rows per wave -> 4096 waves
#define PSTR    136      // f16 plane row stride (272 B: b128-aligned, 2-way banks, room for pad cols 112..127)
#define PLANE   (16 * PSTR)   // one plane in halves; hi+lo = 2*PLANE*2 = 8704 B

typedef _Float16 half8 __attribute__((ext_vector_type(8)));
typedef __fp16   fp16x2 __attribute__((ext_vector_type(2)));   // cvt_pkrtz return type
typedef float    f32x4 __attribute__((ext_vector_type(4)));

// ---------------- workspace layout ----------------
#define WSH_LAYER_HALVES (NT * 4 * 64 * 8)               // 14336 halves per hidden layer
#define WSH_HALVES       (NLAYERS * WSH_LAYER_HALVES)    // 1,433,600
#define W0_HALVES        (NT * 2 * 64 * 8)               // 7168 (input layer, K=64)
#define BPAD_FLOATS      ((NLAYERS + 1) * NPAD)          // 11312 (only row 0 used by main now)
#define OFF_BPAD_B       ((WSH_HALVES + W0_HALVES) * 2)  // bytes, 16-aligned
#define OFF_WOUT_B       (OFF_BPAD_B + BPAD_FLOATS * 4)  // bytes, 16-aligned
#define TOTAL_PREP       (WSH_HALVES + W0_HALVES + BPAD_FLOATS + NPAD)

// ============================================================
// Prep: shuffle weights into MFMA fragment order (f16).
// Fragment (nt,ks), lane(q=lane>>4,l15=lane&15), elem j holds
//   W[k = ks*32 + q*8 + j][n = nt*16 + l15]
// These bytes serve as the A-operand of mfma(Wfrag, hfrag, acc):
//   A[m'=l15][k=q*8+j] = W[k_g][nt*16+m']  (i.e. W^T tile) -- operand swap.
// NEW: row k==112 of each hidden-layer fragment = that layer's bias;
// the h-plane keeps col 112 == 1.0, so MFMA adds the bias for free.
// ============================================================
__global__ void actor_prep(const float* __restrict__ Win, const float* __restrict__ bin,
                           const float* __restrict__ Ws,  const float* __restrict__ bs,
                           const float* __restrict__ Wout,
                           _Float16* __restrict__ wsh, _Float16* __restrict__ w0sh,
                           float* __restrict__ bpad, float* __restrict__ woutp) {
    int t = blockIdx.x * 256 + threadIdx.x;
    if (t < WSH_HALVES) {                       // hidden-layer weights (+ bias row at k=112)
        int j    = t & 7;
        int lane = (t >> 3) & 63;
        int ks   = (t >> 9) & 3;
        int rest = t >> 11;                     // l*7 + nt
        int nt   = rest % 7;
        int l    = rest / 7;
        int qq = lane >> 4, ll = lane & 15;
        int k = ks * 32 + qq * 8 + j;
        int n = nt * 16 + ll;
        float v = 0.f;
        if (k < WDIM && n < WDIM)       v = Ws[(l * WDIM + k) * WDIM + n];
        else if (k == 112 && n < WDIM)  v = bs[l * WDIM + n];   // bias row
        wsh[t] = (_Float16)v;
        return;
    }
    int t2 = t - WSH_HALVES;
    if (t2 < W0_HALVES) {                       // input layer weights (K=64, bias via acc init)
        int j    = t2 & 7;
        int lane = (t2 >> 3) & 63;
        int ks   = (t2 >> 9) & 1;
        int nt   = t2 >> 10;
        int qq = lane >> 4, ll = lane & 15;
        int k = ks * 32 + qq * 8 + j;
        int n = nt * 16 + ll;
        float v = (k < DIN && n < WDIM) ? Win[k * WDIM + n] : 0.f;
        w0sh[t2] = (_Float16)v;
        return;
    }
    int t3 = t2 - W0_HALVES;
    if (t3 < BPAD_FLOATS) {                     // padded biases: row 0 = b_in (acc init for layer 0)
        int l = t3 / NPAD, c = t3 % NPAD;
        float v = 0.f;
        if (c < WDIM) v = (l == 0) ? bin[c] : bs[(l - 1) * WDIM + c];
        bpad[t3] = v;
        return;
    }
    int t4 = t3 - BPAD_FLOATS;
    if (t4 < NPAD) woutp[t4] = (t4 < WDIM) ? Wout[t4] : 0.f;
}

// split fp32 -> hi/lo fp16 (layer-0 input only; hidden layers split in epilogue).
__device__ __forceinline__ void split8(const float* __restrict__ p, half8& hi, half8& lo) {
    f32x4 u0 = *(const f32x4*)p;
    f32x4 u1 = *(const f32x4*)(p + 4);
    float v[8] = {u0[0], u0[1], u0[2], u0[3], u1[0], u1[1], u1[2], u1[3]};
#pragma unroll
    for (int e = 0; e < 8; e += 2) {
        fp16x2 h = __builtin_amdgcn_cvt_pkrtz(v[e], v[e + 1]);
        float r0 = v[e]     - (float)h[0];
        float r1 = v[e + 1] - (float)h[1];
        fp16x2 l = __builtin_amdgcn_cvt_pkrtz(r0, r1);
        hi[e] = (_Float16)h[0]; hi[e + 1] = (_Float16)h[1];
        lo[e] = (_Float16)l[0]; lo[e + 1] = (_Float16)l[1];
    }
}

// ============================================================
// Main: one wave per block, 16 batch rows, whole network fused.
// OPERAND-SWAPPED: D = mfma(Wfrag as A, hfrag as B, acc) computes h^T;
// C layout gives lane(q,l15), reg r -> h_next[batch=l15][neuron=nt*16+q*4+r]:
//   * 4 contiguous neurons per lane -> epilogue = 2 ds_write_b64 per nt
//   * bias rides in W row k=112 against constant 1.0 at h col 112
//   * no pad masking (pad cols 113..127 held at exact zero)
// h planes (hi,lo f16) in LDS; reads are bare ds_read_b128.
// No barriers: wave owns its planes.
// ============================================================
__global__ __launch_bounds__(64, 4)
void actor_main(const float* __restrict__ x,
                const _Float16* __restrict__ wsh,
                const _Float16* __restrict__ w0sh,
                const float* __restrict__ bpad,
                const float* __restrict__ woutp,
                const float* __restrict__ bout,
                float* __restrict__ out) {
    __shared__ _Float16 hp[2 * PLANE];   // [0,PLANE): hi plane; [PLANE,2*PLANE): lo plane
    const int lane = threadIdx.x;
    const int q = lane >> 4, l15 = lane & 15;
    const int rowbase = blockIdx.x * ROWS;

    f32x4 acc[NT];
    half8 wb[2][NT];                 // double-buffered W fragments (A operand), 1 k-step ahead
    const f32x4 zero4 = {0.f, 0.f, 0.f, 0.f};

    // ---- one-time pad init: cols 112..127 zero in both planes, then hi[.,112]=1.0 ----
    {
        const int plane = lane >> 5, row = (lane >> 1) & 15, cg = lane & 1;
        const half8 z = {0, 0, 0, 0, 0, 0, 0, 0};
        *(half8*)(hp + plane * PLANE + row * PSTR + 112 + cg * 8) = z;
        if (lane < 16) hp[lane * PSTR + 112] = (_Float16)1.0f;   // bias multiplier
    }

    // preload input-layer ks=0 W frags; acc init = b_in (padded row 0 of bpad)
#pragma unroll
    for (int nt = 0; nt < NT; ++nt) {
        wb[0][nt] = *(const half8*)(w0sh + ((nt * 2 + 0) * 64 + lane) * 8);
        acc[nt] = *(const f32x4*)(bpad + nt * 16 + q * 4);
    }

    // ---------------- layer 0: x @ W_in (K=64), split from global x ----------------
#pragma unroll
    for (int ks = 0; ks < 2; ++ks) {
        const int cur = ks & 1, nxt = cur ^ 1;
        if (ks == 0) {               // prefetch ks=1
#pragma unroll
            for (int nt = 0; nt < NT; ++nt)
                wb[nxt][nt] = *(const half8*)(w0sh + ((nt * 2 + 1) * 64 + lane) * 8);
        } else {                     // prefetch hidden layer 0, ks=0
#pragma unroll
            for (int nt = 0; nt < NT; ++nt)
                wb[nxt][nt] = *(const half8*)(wsh + ((nt * 4 + 0) * 64 + lane) * 8);
        }
        half8 xhi, xlo;
        split8(x + (rowbase + l15) * DIN + ks * 32 + q * 8, xhi, xlo);
#pragma unroll
        for (int nt = 0; nt < NT; ++nt) {
            acc[nt] = __builtin_amdgcn_mfma_f32_16x16x32_f16(wb[cur][nt], xhi, acc[nt], 0, 0, 0);
            acc[nt] = __builtin_amdgcn_mfma_f32_16x16x32_f16(wb[cur][nt], xlo, acc[nt], 0, 0, 0);
        }
    }
    // epilogue 0: leaky + split + packed b64 stores (pad neurons 100..111 stay exact 0)
#pragma unroll
    for (int nt = 0; nt < NT; ++nt) {
        float v0 = fmaxf(acc[nt][0], 0.01f * acc[nt][0]);
        float v1 = fmaxf(acc[nt][1], 0.01f * acc[nt][1]);
        float v2 = fmaxf(acc[nt][2], 0.01f * acc[nt][2]);
        float v3 = fmaxf(acc[nt][3], 0.01f * acc[nt][3]);
        fp16x2 h01 = __builtin_amdgcn_cvt_pkrtz(v0, v1);
        fp16x2 h23 = __builtin_amdgcn_cvt_pkrtz(v2, v3);
        fp16x2 l01 = __builtin_amdgcn_cvt_pkrtz(v0 - (float)h01[0], v1 - (float)h01[1]);
        fp16x2 l23 = __builtin_amdgcn_cvt_pkrtz(v2 - (float)h23[0], v3 - (float)h23[1]);
        const int idx = l15 * PSTR + nt * 16 + q * 4;
        uint2 hw; hw.x = __builtin_bit_cast(unsigned, h01); hw.y = __builtin_bit_cast(unsigned, h23);
        uint2 lw; lw.x = __builtin_bit_cast(unsigned, l01); lw.y = __builtin_bit_cast(unsigned, l23);
        *reinterpret_cast<uint2*>(hp + idx) = hw;
        *reinterpret_cast<uint2*>(hp + PLANE + idx) = lw;
    }

    // ---------------- 100 hidden layers ----------------
#pragma unroll 1
    for (int l = 0; l < NLAYERS; ++l) {
        const _Float16* wl = wsh + l * WSH_LAYER_HALVES;
        const _Float16* wlnext = wsh + (l < NLAYERS - 1 ? l + 1 : l) * WSH_LAYER_HALVES;
#pragma unroll
        for (int nt = 0; nt < NT; ++nt) acc[nt] = zero4;   // bias comes via k=112 row

#pragma unroll
        for (int ks = 0; ks < 4; ++ks) {
            const int cur = ks & 1, nxt = cur ^ 1;
            // prefetch next k-step (or next layer's ks=0) W frags
            const _Float16* src = (ks < 3) ? (wl + ((ks + 1) * 64 + lane) * 8)
                                           : (wlnext + (lane) * 8);
#pragma unroll
            for (int nt = 0; nt < NT; ++nt)
                wb[nxt][nt] = *(const half8*)(src + nt * 4 * 64 * 8);

            // hi fragment: bare b128 (ks=3 covers bias col 112=1.0 and zero pads)
            half8 bhi = *(const half8*)(hp + l15 * PSTR + ks * 32 + q * 8);
#pragma unroll
            for (int nt = 0; nt < NT; ++nt)
                acc[nt] = __builtin_amdgcn_mfma_f32_16x16x32_f16(wb[cur][nt], bhi, acc[nt], 0, 0, 0);

            if (ks < 3) {            // lo correction (ks=3 lo covers only k 96..99: negligible)
                half8 blo = *(const half8*)(hp + PLANE + l15 * PSTR + ks * 32 + q * 8);
#pragma unroll
                for (int nt = 0; nt < NT; ++nt)
                    acc[nt] = __builtin_amdgcn_mfma_f32_16x16x32_f16(wb[cur][nt], blo, acc[nt], 0, 0, 0);
            }
        }
        // epilogue: leaky + split + packed b64 stores
#pragma unroll
        for (int nt = 0; nt < NT; ++nt) {
            float v0 = fmaxf(acc[nt][0], 0.01f * acc[nt][0]);
            float v1 = fmaxf(acc[nt][1], 0.01f * acc[nt][1]);
            float v2 = fmaxf(acc[nt][2], 0.01f * acc[nt][2]);
            float v3 = fmaxf(acc[nt][3], 0.01f * acc[nt][3]);
            fp16x2 h01 = __builtin_amdgcn_cvt_pkrtz(v0, v1);
            fp16x2 h23 = __builtin_amdgcn_cvt_pkrtz(v2, v3);
            fp16x2 l01 = __builtin_amdgcn_cvt_pkrtz(v0 - (float)h01[0], v1 - (float)h01[1]);
            fp16x2 l23 = __builtin_amdgcn_cvt_pkrtz(v2 - (float)h23[0], v3 - (float)h23[1]);
            const int idx = l15 * PSTR + nt * 16 + q * 4;
            uint2 hw; hw.x = __builtin_bit_cast(unsigned, h01); hw.y = __builtin_bit_cast(unsigned, h23);
            uint2 lw; lw.x = __builtin_bit_cast(unsigned, l01); lw.y = __builtin_bit_cast(unsigned, l23);
            *reinterpret_cast<uint2*>(hp + idx) = hw;
            *reinterpret_cast<uint2*>(hp + PLANE + idx) = lw;
        }
    }

    // ---------------- head: dot(h, W_out) + b_out, tanh, affine ----------------
    {
        const int row = lane >> 2, hf = lane & 3;   // 4 lanes per row, 28 cols each (cols<112)
        float s = 0.f;
#pragma unroll
        for (int i = 0; i < 28; ++i) {
            const int c = hf * 28 + i;
            float v = (float)hp[row * PSTR + c] + (float)hp[PLANE + row * PSTR + c];
            s += v * woutp[c];
        }
        s += __shfl_xor(s, 1);
        s += __shfl_xor(s, 2);
        if (hf == 0) {
            float a = s + bout[0];
            float t = tanhf(a);
            out[rowbase + row] = t * 4.5f + 5.5f;   // (tanh+1)/2*9 + 1
        }
    }
}

extern "C" void kernel_launch(void* const* d_in, const int* in_sizes, int n_in,
                              void* d_out, int out_size, void* d_ws, size_t ws_size,
                              hipStream_t stream) {
    const float* x    = (const float*)d_in[0];
    const float* Win  = (const float*)d_in[1];
    const float* bin  = (const float*)d_in[2];
    const float* Ws   = (const float*)d_in[3];
    const float* bs   = (const float*)d_in[4];
    const float* Wout = (const float*)d_in[5];
    const float* bout = (const float*)d_in[6];
    float* out = (float*)d_out;

    char* ws = (char*)d_ws;
    _Float16* wsh  = (_Float16*)ws;
    _Float16* w0sh = wsh + WSH_HALVES;
    float* bpad  = (float*)(ws + OFF_BPAD_B);
    float* woutp = (float*)(ws + OFF_WOUT_B);

    hipLaunchKernelGGL(actor_prep, dim3((TOTAL_PREP + 255) / 256), dim3(256), 0, stream,
                       Win, bin, Ws, bs, Wout, wsh, w0sh, bpad, woutp);

    const int nrows = in_sizes[0] / DIN;   // 65536
    hipLaunchKernelGGL(actor_main, dim3(nrows / ROWS), dim3(64), 0, stream,
                       x, wsh, w0sh, bpad, woutp, bout, out);
}

// Round 6
// 444.866 us; speedup vs baseline: 1.1384x; 1.0603x over previous
//
#include <hip/hip_runtime.h>
#include <cmath>

// ---------------- problem constants ----------------
#define NLAYERS 100      // hidden layers (scan)
#define DIN     64       // input features
#define WDIM    100      // hidden width
#define NPAD    112      // padded N (7 tiles of 16)
#define NT      7        // n tiles
#define RT      2        // row tiles -> 32 batch rows/wave; W-frags reused across both
#define ROWS    32
#define PSTR    136      // f16 plane row stride (272 B: b128-aligned, room for pad cols 112..127)
#define PLANE   (16 * PSTR)   // one plane (one row-tile, one of hi/lo) in halves

typedef _Float16 half8 __attribute__((ext_vector_type(8)));
typedef __fp16   fp16x2 __attribute__((ext_vector_type(2)));   // cvt_pkrtz return type
typedef float    f32x4 __attribute__((ext_vector_type(4)));

// ---------------- workspace layout ----------------
#define WSH_LAYER_HALVES (NT * 4 * 64 * 8)               // 14336 halves per hidden layer
#define WSH_HALVES       (NLAYERS * WSH_LAYER_HALVES)    // 1,433,600
#define W0_HALVES        (NT * 2 * 64 * 8)               // 7168 (input layer, K=64)
#define BPAD_FLOATS      ((NLAYERS + 1) * NPAD)          // 11312 (row 0 = b_in used as acc init)
#define OFF_BPAD_B       ((WSH_HALVES + W0_HALVES) * 2)  // bytes, 16-aligned
#define OFF_WOUT_B       (OFF_BPAD_B + BPAD_FLOATS * 4)  // bytes, 16-aligned
#define TOTAL_PREP       (WSH_HALVES + W0_HALVES + BPAD_FLOATS + NPAD)

// ============================================================
// Prep: shuffle weights into MFMA A-operand order (f16), operand-swapped
// (see round-5 notes): frag (nt,ks), lane(q,l15), elem j holds
//   W[k = ks*32 + q*8 + j][n = nt*16 + l15]
// Row k==112 of each hidden-layer fragment = layer bias (h col 112 == 1.0).
// ============================================================
__global__ void actor_prep(const float* __restrict__ Win, const float* __restrict__ bin,
                           const float* __restrict__ Ws,  const float* __restrict__ bs,
                           const float* __restrict__ Wout,
                           _Float16* __restrict__ wsh, _Float16* __restrict__ w0sh,
                           float* __restrict__ bpad, float* __restrict__ woutp) {
    int t = blockIdx.x * 256 + threadIdx.x;
    if (t < WSH_HALVES) {                       // hidden-layer weights (+ bias row at k=112)
        int j    = t & 7;
        int lane = (t >> 3) & 63;
        int ks   = (t >> 9) & 3;
        int rest = t >> 11;                     // l*7 + nt
        int nt   = rest % 7;
        int l    = rest / 7;
        int qq = lane >> 4, ll = lane & 15;
        int k = ks * 32 + qq * 8 + j;
        int n = nt * 16 + ll;
        float v = 0.f;
        if (k < WDIM && n < WDIM)       v = Ws[(l * WDIM + k) * WDIM + n];
        else if (k == 112 && n < WDIM)  v = bs[l * WDIM + n];   // bias row
        wsh[t] = (_Float16)v;
        return;
    }
    int t2 = t - WSH_HALVES;
    if (t2 < W0_HALVES) {                       // input layer weights (K=64, bias via acc init)
        int j    = t2 & 7;
        int lane = (t2 >> 3) & 63;
        int ks   = (t2 >> 9) & 1;
        int nt   = t2 >> 10;
        int qq = lane >> 4, ll = lane & 15;
        int k = ks * 32 + qq * 8 + j;
        int n = nt * 16 + ll;
        float v = (k < DIN && n < WDIM) ? Win[k * WDIM + n] : 0.f;
        w0sh[t2] = (_Float16)v;
        return;
    }
    int t3 = t2 - W0_HALVES;
    if (t3 < BPAD_FLOATS) {                     // padded biases: row 0 = b_in
        int l = t3 / NPAD, c = t3 % NPAD;
        float v = 0.f;
        if (c < WDIM) v = (l == 0) ? bin[c] : bs[(l - 1) * WDIM + c];
        bpad[t3] = v;
        return;
    }
    int t4 = t3 - BPAD_FLOATS;
    if (t4 < NPAD) woutp[t4] = (t4 < WDIM) ? Wout[t4] : 0.f;
}

// split fp32 -> hi/lo fp16 (layer-0 input only; hidden layers split in epilogue).
__device__ __forceinline__ void split8(const float* __restrict__ p, half8& hi, half8& lo) {
    f32x4 u0 = *(const f32x4*)p;
    f32x4 u1 = *(const f32x4*)(p + 4);
    float v[8] = {u0[0], u0[1], u0[2], u0[3], u1[0], u1[1], u1[2], u1[3]};
#pragma unroll
    for (int e = 0; e < 8; e += 2) {
        fp16x2 h = __builtin_amdgcn_cvt_pkrtz(v[e], v[e + 1]);
        float r0 = v[e]     - (float)h[0];
        float r1 = v[e + 1] - (float)h[1];
        fp16x2 l = __builtin_amdgcn_cvt_pkrtz(r0, r1);
        hi[e] = (_Float16)h[0]; hi[e + 1] = (_Float16)h[1];
        lo[e] = (_Float16)l[0]; lo[e + 1] = (_Float16)l[1];
    }
}

// ============================================================
// Main: one wave per block, 32 batch rows (2 row-tiles), network fused.
// Operand-swapped mfma(Wfrag, hfrag, acc): ONE set of 28 W-frag loads/layer
// feeds BOTH row-tiles -> weight L2 traffic halved vs 16-row waves, and
// 14 independent acc chains for ILP. Bias rides W row k=112 vs h col 112=1.0.
// h planes (hi,lo f16) per row-tile in LDS; reads bare ds_read_b128.
// No barriers: wave owns its planes. 2048 blocks = 2 waves/SIMD.
// ============================================================
__global__ __launch_bounds__(64, 2)
void actor_main(const float* __restrict__ x,
                const _Float16* __restrict__ wsh,
                const _Float16* __restrict__ w0sh,
                const float* __restrict__ bpad,
                const float* __restrict__ woutp,
                const float* __restrict__ bout,
                float* __restrict__ out) {
    __shared__ _Float16 hp[2 * 2 * PLANE];   // [rt][plane] planes; plane0=hi, plane1=lo
    const int lane = threadIdx.x;
    const int q = lane >> 4, l15 = lane & 15;
    const int rowbase = blockIdx.x * ROWS;

    f32x4 acc[RT][NT];
    half8 wb[2][NT];                 // double-buffered W fragments (A operand), 1 k-step ahead
    const f32x4 zero4 = {0.f, 0.f, 0.f, 0.f};

    // ---- one-time pad init: cols 112..127 zero in all 4 planes, hi[.,112]=1.0 ----
    {
        const int pl = lane >> 4, row = lane & 15;    // pl in [0,4): (rt*2+plane)
        const half8 z = {0, 0, 0, 0, 0, 0, 0, 0};
        *(half8*)(hp + pl * PLANE + row * PSTR + 112) = z;
        *(half8*)(hp + pl * PLANE + row * PSTR + 120) = z;
    }
    {
        if (lane < 32) {
            const int rt = lane >> 4, row = lane & 15;
            hp[(rt * 2 + 0) * PLANE + row * PSTR + 112] = (_Float16)1.0f;  // bias multiplier
        }
    }

    // preload input-layer ks=0 W frags; acc init = b_in
#pragma unroll
    for (int nt = 0; nt < NT; ++nt) {
        wb[0][nt] = *(const half8*)(w0sh + ((nt * 2 + 0) * 64 + lane) * 8);
        f32x4 b = *(const f32x4*)(bpad + nt * 16 + q * 4);
        acc[0][nt] = b;
        acc[1][nt] = b;
    }

    // ---------------- layer 0: x @ W_in (K=64), split from global x ----------------
#pragma unroll
    for (int ks = 0; ks < 2; ++ks) {
        const int cur = ks & 1, nxt = cur ^ 1;
        if (ks == 0) {               // prefetch ks=1
#pragma unroll
            for (int nt = 0; nt < NT; ++nt)
                wb[nxt][nt] = *(const half8*)(w0sh + ((nt * 2 + 1) * 64 + lane) * 8);
        } else {                     // prefetch hidden layer 0, ks=0
#pragma unroll
            for (int nt = 0; nt < NT; ++nt)
                wb[nxt][nt] = *(const half8*)(wsh + ((nt * 4 + 0) * 64 + lane) * 8);
        }
#pragma unroll
        for (int rt = 0; rt < RT; ++rt) {
            half8 xhi, xlo;
            split8(x + (rowbase + rt * 16 + l15) * DIN + ks * 32 + q * 8, xhi, xlo);
#pragma unroll
            for (int nt = 0; nt < NT; ++nt) {
                acc[rt][nt] = __builtin_amdgcn_mfma_f32_16x16x32_f16(wb[cur][nt], xhi, acc[rt][nt], 0, 0, 0);
                acc[rt][nt] = __builtin_amdgcn_mfma_f32_16x16x32_f16(wb[cur][nt], xlo, acc[rt][nt], 0, 0, 0);
            }
        }
    }
    // epilogue 0: leaky + split + packed b64 stores (pad neurons 100..111 stay exact 0)
#pragma unroll
    for (int rt = 0; rt < RT; ++rt)
#pragma unroll
        for (int nt = 0; nt < NT; ++nt) {
            f32x4 a = acc[rt][nt];
            float v0 = fmaxf(a[0], 0.01f * a[0]);
            float v1 = fmaxf(a[1], 0.01f * a[1]);
            float v2 = fmaxf(a[2], 0.01f * a[2]);
            float v3 = fmaxf(a[3], 0.01f * a[3]);
            fp16x2 h01 = __builtin_amdgcn_cvt_pkrtz(v0, v1);
            fp16x2 h23 = __builtin_amdgcn_cvt_pkrtz(v2, v3);
            fp16x2 l01 = __builtin_amdgcn_cvt_pkrtz(v0 - (float)h01[0], v1 - (float)h01[1]);
            fp16x2 l23 = __builtin_amdgcn_cvt_pkrtz(v2 - (float)h23[0], v3 - (float)h23[1]);
            const int idx = l15 * PSTR + nt * 16 + q * 4;
            uint2 hw; hw.x = __builtin_bit_cast(unsigned, h01); hw.y = __builtin_bit_cast(unsigned, h23);
            uint2 lw; lw.x = __builtin_bit_cast(unsigned, l01); lw.y = __builtin_bit_cast(unsigned, l23);
            *reinterpret_cast<uint2*>(hp + (rt * 2 + 0) * PLANE + idx) = hw;
            *reinterpret_cast<uint2*>(hp + (rt * 2 + 1) * PLANE + idx) = lw;
        }

    // ---------------- 100 hidden layers ----------------
#pragma unroll 1
    for (int l = 0; l < NLAYERS; ++l) {
        const _Float16* wl = wsh + l * WSH_LAYER_HALVES;
        const _Float16* wlnext = wsh + (l < NLAYERS - 1 ? l + 1 : l) * WSH_LAYER_HALVES;
#pragma unroll
        for (int rt = 0; rt < RT; ++rt)
#pragma unroll
            for (int nt = 0; nt < NT; ++nt) acc[rt][nt] = zero4;   // bias via k=112 row

#pragma unroll
        for (int ks = 0; ks < 4; ++ks) {
            const int cur = ks & 1, nxt = cur ^ 1;
            // prefetch next k-step (or next layer's ks=0) W frags — shared by both row-tiles
            const _Float16* src = (ks < 3) ? (wl + ((ks + 1) * 64 + lane) * 8)
                                           : (wlnext + (lane) * 8);
#pragma unroll
            for (int nt = 0; nt < NT; ++nt)
                wb[nxt][nt] = *(const half8*)(src + nt * 4 * 64 * 8);

#pragma unroll
            for (int rt = 0; rt < RT; ++rt) {
                // hi fragment: bare b128 (ks=3 covers bias col 112=1.0 and zero pads)
                half8 bhi = *(const half8*)(hp + (rt * 2 + 0) * PLANE + l15 * PSTR + ks * 32 + q * 8);
#pragma unroll
                for (int nt = 0; nt < NT; ++nt)
                    acc[rt][nt] = __builtin_amdgcn_mfma_f32_16x16x32_f16(wb[cur][nt], bhi, acc[rt][nt], 0, 0, 0);
            }
            if (ks < 3) {            // lo correction (ks=3 lo covers only k 96..99: negligible)
#pragma unroll
                for (int rt = 0; rt < RT; ++rt) {
                    half8 blo = *(const half8*)(hp + (rt * 2 + 1) * PLANE + l15 * PSTR + ks * 32 + q * 8);
#pragma unroll
                    for (int nt = 0; nt < NT; ++nt)
                        acc[rt][nt] = __builtin_amdgcn_mfma_f32_16x16x32_f16(wb[cur][nt], blo, acc[rt][nt], 0, 0, 0);
                }
            }
        }
        // epilogue: leaky + split + packed b64 stores
#pragma unroll
        for (int rt = 0; rt < RT; ++rt)
#pragma unroll
            for (int nt = 0; nt < NT; ++nt) {
                f32x4 a = acc[rt][nt];
                float v0 = fmaxf(a[0], 0.01f * a[0]);
                float v1 = fmaxf(a[1], 0.01f * a[1]);
                float v2 = fmaxf(a[2], 0.01f * a[2]);
                float v3 = fmaxf(a[3], 0.01f * a[3]);
                fp16x2 h01 = __builtin_amdgcn_cvt_pkrtz(v0, v1);
                fp16x2 h23 = __builtin_amdgcn_cvt_pkrtz(v2, v3);
                fp16x2 l01 = __builtin_amdgcn_cvt_pkrtz(v0 - (float)h01[0], v1 - (float)h01[1]);
                fp16x2 l23 = __builtin_amdgcn_cvt_pkrtz(v2 - (float)h23[0], v3 - (float)h23[1]);
                const int idx = l15 * PSTR + nt * 16 + q * 4;
                uint2 hw; hw.x = __builtin_bit_cast(unsigned, h01); hw.y = __builtin_bit_cast(unsigned, h23);
                uint2 lw; lw.x = __builtin_bit_cast(unsigned, l01); lw.y = __builtin_bit_cast(unsigned, l23);
                *reinterpret_cast<uint2*>(hp + (rt * 2 + 0) * PLANE + idx) = hw;
                *reinterpret_cast<uint2*>(hp + (rt * 2 + 1) * PLANE + idx) = lw;
            }
    }

    // ---------------- head: dot(h, W_out) + b_out, tanh, affine ----------------
    {
        const int row = lane >> 1, hf = lane & 1;   // 2 lanes per row, 56 cols each (pads are 0)
        const int rt = row >> 4, r15 = row & 15;
        const _Float16* hpp = hp + (rt * 2 + 0) * PLANE + r15 * PSTR;
        const _Float16* lpp = hp + (rt * 2 + 1) * PLANE + r15 * PSTR;
        float s = 0.f;
#pragma unroll
        for (int i = 0; i < 56; ++i) {
            const int c = hf * 56 + i;
            float v = (float)hpp[c] + (float)lpp[c];
            s += v * woutp[c];
        }
        s += __shfl_xor(s, 1);
        if (hf == 0) {
            float a = s + bout[0];
            float t = tanhf(a);
            out[rowbase + row] = t * 4.5f + 5.5f;   // (tanh+1)/2*9 + 1
        }
    }
}

extern "C" void kernel_launch(void* const* d_in, const int* in_sizes, int n_in,
                              void* d_out, int out_size, void* d_ws, size_t ws_size,
                              hipStream_t stream) {
    const float* x    = (const float*)d_in[0];
    const float* Win  = (const float*)d_in[1];
    const float* bin  = (const float*)d_in[2];
    const float* Ws   = (const float*)d_in[3];
    const float* bs   = (const float*)d_in[4];
    const float* Wout = (const float*)d_in[5];
    const float* bout = (const float*)d_in[6];
    float* out = (float*)d_out;

    char* ws = (char*)d_ws;
    _Float16* wsh  = (_Float16*)ws;
    _Float16* w0sh = wsh + WSH_HALVES;
    float* bpad  = (float*)(ws + OFF_BPAD_B);
    float* woutp = (float*)(ws + OFF_WOUT_B);

    hipLaunchKernelGGL(actor_prep, dim3((TOTAL_PREP + 255) / 256), dim3(256), 0, stream,
                       Win, bin, Ws, bs, Wout, wsh, w0sh, bpad, woutp);

    const int nrows = in_sizes[0] / DIN;   // 65536
    hipLaunchKernelGGL(actor_main, dim3(nrows / ROWS), dim3(64), 0, stream,
                       x, wsh, w0sh, bpad, woutp, bout, out);
}